// Round 1
// baseline (4697.397 us; speedup 1.0000x reference)
//
#include <hip/hip_runtime.h>
#include <cstdint>
#include <cstddef>

#define BB 64
#define SS 2048
#define FF 128
#define HH 256
#define CC 10

// ---------------------------------------------------------------------------
// GEMM: out[m,n] = sum_k X[m,k] * W[n,k] + b1[n] + b2[n]
// X: [M, K] row-major, W: [HH, K] row-major, out: [M, HH]
// BM=64, BN=64, BK=32 LDS tiles, 256 threads, 4x4 micro-tile per thread.
// ---------------------------------------------------------------------------
template<int K>
__global__ __launch_bounds__(256)
void xproj_gemm(const float* __restrict__ X, const float* __restrict__ W,
                const float* __restrict__ b1, const float* __restrict__ b2,
                float* __restrict__ out)
{
    constexpr int BM = 64, BN = 64, BK = 32;
    __shared__ float As[BK][BM + 4];   // +4 pad: keeps float4 alignment, ~4-way store conflict max
    __shared__ float Ws[BK][BN + 4];

    const int m0 = blockIdx.x * BM;
    const int n0 = blockIdx.y * BN;
    const int tid = (int)threadIdx.x;
    const int tm = tid & 15;        // 0..15 -> 4 rows each
    const int tn = tid >> 4;        // 0..15 -> 4 cols each
    const int lr = tid >> 3;        // 0..31 loader row
    const int lc = tid & 7;         // 0..7  loader k-group (x4)

    float acc[4][4];
    #pragma unroll
    for (int i = 0; i < 4; ++i)
        #pragma unroll
        for (int jj = 0; jj < 4; ++jj) acc[i][jj] = 0.f;

    for (int k0 = 0; k0 < K; k0 += BK) {
        float4 a0 = *(const float4*)&X[(size_t)(m0 + lr) * K + k0 + lc * 4];
        float4 a1 = *(const float4*)&X[(size_t)(m0 + lr + 32) * K + k0 + lc * 4];
        float4 w0 = *(const float4*)&W[(size_t)(n0 + lr) * K + k0 + lc * 4];
        float4 w1 = *(const float4*)&W[(size_t)(n0 + lr + 32) * K + k0 + lc * 4];
        As[lc*4+0][lr]    = a0.x; As[lc*4+1][lr]    = a0.y; As[lc*4+2][lr]    = a0.z; As[lc*4+3][lr]    = a0.w;
        As[lc*4+0][lr+32] = a1.x; As[lc*4+1][lr+32] = a1.y; As[lc*4+2][lr+32] = a1.z; As[lc*4+3][lr+32] = a1.w;
        Ws[lc*4+0][lr]    = w0.x; Ws[lc*4+1][lr]    = w0.y; Ws[lc*4+2][lr]    = w0.z; Ws[lc*4+3][lr]    = w0.w;
        Ws[lc*4+0][lr+32] = w1.x; Ws[lc*4+1][lr+32] = w1.y; Ws[lc*4+2][lr+32] = w1.z; Ws[lc*4+3][lr+32] = w1.w;
        __syncthreads();
        #pragma unroll
        for (int k = 0; k < BK; ++k) {
            float4 av = *(const float4*)&As[k][tm * 4];
            float4 wv = *(const float4*)&Ws[k][tn * 4];
            acc[0][0] = fmaf(av.x, wv.x, acc[0][0]);
            acc[0][1] = fmaf(av.x, wv.y, acc[0][1]);
            acc[0][2] = fmaf(av.x, wv.z, acc[0][2]);
            acc[0][3] = fmaf(av.x, wv.w, acc[0][3]);
            acc[1][0] = fmaf(av.y, wv.x, acc[1][0]);
            acc[1][1] = fmaf(av.y, wv.y, acc[1][1]);
            acc[1][2] = fmaf(av.y, wv.z, acc[1][2]);
            acc[1][3] = fmaf(av.y, wv.w, acc[1][3]);
            acc[2][0] = fmaf(av.z, wv.x, acc[2][0]);
            acc[2][1] = fmaf(av.z, wv.y, acc[2][1]);
            acc[2][2] = fmaf(av.z, wv.z, acc[2][2]);
            acc[2][3] = fmaf(av.z, wv.w, acc[2][3]);
            acc[3][0] = fmaf(av.w, wv.x, acc[3][0]);
            acc[3][1] = fmaf(av.w, wv.y, acc[3][1]);
            acc[3][2] = fmaf(av.w, wv.z, acc[3][2]);
            acc[3][3] = fmaf(av.w, wv.w, acc[3][3]);
        }
        __syncthreads();
    }

    float4 bv1 = *(const float4*)&b1[n0 + tn * 4];
    float4 bv2 = *(const float4*)&b2[n0 + tn * 4];
    float bs0 = bv1.x + bv2.x, bs1 = bv1.y + bv2.y, bs2 = bv1.z + bv2.z, bs3 = bv1.w + bv2.w;
    #pragma unroll
    for (int i = 0; i < 4; ++i) {
        float4 o;
        o.x = acc[i][0] + bs0;
        o.y = acc[i][1] + bs1;
        o.z = acc[i][2] + bs2;
        o.w = acc[i][3] + bs3;
        *(float4*)&out[(size_t)(m0 + tm * 4 + i) * HH + n0 + tn * 4] = o;
    }
}

// ---------------------------------------------------------------------------
// Sequential Elman scan for one layer.
// One block per batch element (64 blocks). 512 threads: output row j = tid>>1,
// dot-half = tid&1 (128 fp32 weights per thread in VGPRs). h double-buffered
// in LDS. Optionally writes full h sequence (for the next layer's xproj GEMM)
// and optionally applies the final linear head (last layer).
// ---------------------------------------------------------------------------
__global__ __launch_bounds__(512, 2)
void rnn_scan(const float* __restrict__ xproj,   // [B,S,H] precomputed x-projection + biases
              const float* __restrict__ Whh,     // [H,H]
              float* __restrict__ hout,          // [B,S,H] or nullptr
              const float* __restrict__ Wd,      // [C,H] or nullptr
              const float* __restrict__ bd,      // [C] or nullptr
              float* __restrict__ outfinal,      // [B,C] or nullptr
              int storeH)
{
    __shared__ float hbuf[2][HH];
    const int b = blockIdx.x;
    const int tid = (int)threadIdx.x;
    const int j = tid >> 1;        // output row 0..255
    const int half = tid & 1;      // which half of the dot product

    // Load my 128 weights into registers (one-time, amortized over 2048 steps)
    float w[128];
    const float* wrow = Whh + (size_t)j * HH + half * 128;
    #pragma unroll
    for (int k = 0; k < 128; k += 4) {
        float4 v = *(const float4*)&wrow[k];
        w[k] = v.x; w[k + 1] = v.y; w[k + 2] = v.z; w[k + 3] = v.w;
    }
    if (tid < HH) hbuf[0][tid] = 0.f;
    __syncthreads();

    const float* xp = xproj + (size_t)b * SS * HH;
    float* ho = hout ? hout + (size_t)b * SS * HH : nullptr;
    int cur = 0;
    float xpv = xp[j];             // prefetch t=0
    for (int t = 0; t < SS; ++t) {
        // prefetch next step's xproj value (independent of this step's result)
        float xpn = 0.f;
        if (t + 1 < SS) xpn = xp[(size_t)(t + 1) * HH + j];

        const float* hc = &hbuf[cur][half * 128];
        float a0 = 0.f, a1 = 0.f, a2 = 0.f, a3 = 0.f;
        #pragma unroll
        for (int k = 0; k < 128; k += 4) {
            float4 h4 = *(const float4*)&hc[k];   // LDS broadcast read (2 addrs/wave: free)
            a0 = fmaf(w[k + 0], h4.x, a0);
            a1 = fmaf(w[k + 1], h4.y, a1);
            a2 = fmaf(w[k + 2], h4.z, a2);
            a3 = fmaf(w[k + 3], h4.w, a3);
        }
        float accv = (a0 + a1) + (a2 + a3);
        accv += __shfl_xor(accv, 1);              // combine the two half-dots (adjacent lanes)
        float z = xpv + accv;
        // tanh(z) = 1 - 2/(exp(2z)+1): no NaN for any finite z (inf -> 1, 0 -> -1)
        float e = __expf(2.f * z);
        float ht = 1.f - 2.f / (e + 1.f);
        if (half == 0) {
            hbuf[cur ^ 1][j] = ht;
            if (storeH) ho[(size_t)t * HH + j] = ht;
        }
        __syncthreads();
        cur ^= 1;
        xpv = xpn;
    }

    // Final linear head: out[b,c] = dot(h_last, Wd[c,:]) + bd[c]
    if (outfinal != nullptr && tid < CC) {
        const float* wd = Wd + (size_t)tid * HH;
        float a = bd[tid];
        #pragma unroll 4
        for (int k = 0; k < HH; ++k) a = fmaf(hbuf[cur][k], wd[k], a);
        outfinal[(size_t)b * CC + tid] = a;
    }
}

// ---------------------------------------------------------------------------
extern "C" void kernel_launch(void* const* d_in, const int* in_sizes, int n_in,
                              void* d_out, int out_size, void* d_ws, size_t ws_size,
                              hipStream_t stream)
{
    const float* x    = (const float*)d_in[0];
    const float* Wih0 = (const float*)d_in[1];
    const float* Whh0 = (const float*)d_in[2];
    const float* bih0 = (const float*)d_in[3];
    const float* bhh0 = (const float*)d_in[4];
    const float* Wih1 = (const float*)d_in[5];
    const float* Whh1 = (const float*)d_in[6];
    const float* bih1 = (const float*)d_in[7];
    const float* bhh1 = (const float*)d_in[8];
    const float* Wd   = (const float*)d_in[9];
    const float* bd   = (const float*)d_in[10];
    float* out = (float*)d_out;

    float* xp = (float*)d_ws;                          // [B*S*H] fp32 = 134 MB
    float* h1 = xp + (size_t)BB * SS * HH;             // [B*S*H] fp32 = 134 MB

    dim3 gemm_grid(BB * SS / 64, HH / 64);             // (2048, 4)

    // Layer 0: xproj0 = x @ Wih0^T + (bih0+bhh0), then scan (stores h1 sequence)
    xproj_gemm<FF><<<gemm_grid, 256, 0, stream>>>(x, Wih0, bih0, bhh0, xp);
    rnn_scan<<<BB, 512, 0, stream>>>(xp, Whh0, h1, nullptr, nullptr, nullptr, 1);

    // Layer 1: xproj1 = h1 @ Wih1^T + (bih1+bhh1) (reuses xp buffer), then scan + head
    xproj_gemm<HH><<<gemm_grid, 256, 0, stream>>>(h1, Wih1, bih1, bhh1, xp);
    rnn_scan<<<BB, 512, 0, stream>>>(xp, Whh1, nullptr, Wd, bd, out, 0);
}